// Round 7
// baseline (452.336 us; speedup 1.0000x reference)
//
#include <hip/hip_runtime.h>
#include <hip/hip_bf16.h>

// out[b,k,oc,x] = sum_i W[k,oc,i] * in[b,i,k,x] + bias[k,oc]
// B=4096, Cin=Cout=128, K(offsets)=9, X=9.
// Memory-bound. Traffic floor ~350 MB (in 170 + out 170 + W*8XCD) -> ~58us @6TB/s.
// R1: XCD swizzle + W direct.                      (158us)
// R2: deep-MLP staging -> null.                    (164us)
// R3: LDS-relayout coalesced stores -> -13%.       (143us)
// R4: all-k 512-thr blocks -> regression.          (249us)
// R5: 64-reg budget spill.                         (322us)
// R6: pipeline, LDS slot swap bug.                 (failed)
// R7: pipeline works: 2.97 TB/s sustained, time == bytes/BW (latency class
//     dead). But KG=3 partial-row reads amplify FETCH 1.6x (274 MB).  (151us)
// R8: KG=9 (block owns all 9 k's of 4 b-rows): k-steps read address-adjacent
//     36B slices -> boundary lines L1/L2-hit within the block, FETCH -> ~205MB.
//     BT=4 halves LDS to 28.2KB -> 4 blk/CU (100% occupancy) at (512,8);
//     reg audit vs R7's measured 60: ~50-55 peak, fits 64 cap. Pipeline,
//     FIFO W-before-prefetch, lgkm-only barriers unchanged from R7.

#define NB    4096
#define CINC  128
#define COUTC 128
#define NK    9
#define NX    9
#define BT    4                // b's per block
#define NCOL  (BT * NX)        // 36 cols
#define LDK   136              // padded i-stride (shorts)
#define ROWF  (NK * NX)        // 81 floats per (b,i) row
#define OUTK  (COUTC * NX)     // 1152 floats per (b,k)
#define OUTB  (NK * OUTK)

typedef __attribute__((ext_vector_type(8))) short short8;
typedef __attribute__((ext_vector_type(4))) float floatx4;

struct F4 { float x, y, z, w; };   // 16B payload, 4B-aligned -> global_load_dwordx4

__device__ __forceinline__ short f2bf(float f) {
    union { float f; unsigned u; } v; v.f = f;
    unsigned r = v.u + 0x7fff + ((v.u >> 16) & 1);  // RNE; inputs finite normals
    return (short)(r >> 16);
}

__global__ __launch_bounds__(512, 8) void GatherVertical_40656160424516_kernel(
    const float* __restrict__ in, const float* __restrict__ w,
    const float* __restrict__ bias, float* __restrict__ out)
{
    // Il: bf16 [col=bl*9+x : 36][i : LDK] =  9792 B  (MFMA operand tile)
    // Ol: f32  [bl : 4][oc : 128][x : 9]  = 18432 B  (epilogue relayout)
    // 28224 B total -> 4 blocks/CU (wave-limited), the occupancy lever.
    __shared__ __align__(16) char smem[NCOL * LDK * 2 + BT * OUTK * 4];
    short* Il = (short*)smem;
    float* Ol = (float*)(smem + NCOL * LDK * 2);

    const int t = threadIdx.x;
    const int b0 = blockIdx.x * BT;   // blocks fully private: no swizzle needed

    const int lane = t & 63;
    const int wv = t >> 6;            // 0..7: wave's 16 oc rows
    const int lc = lane & 15;
    const int quad = lane >> 4;
    const int oc_base = wv * 16;

    // ---- staging decomposition: thread t owns row (bl = t>>7, i = t&127).
    // Per k-tile: 2x dwordx4 + 1 dword (9 floats, 36B of the row), then
    // 9 ds_write_b16 at one base + imm offsets (lanes = consecutive i ->
    // 2-way bank alias = free).
    const int i_st = t & 127;
    const int bl_st = t >> 7;
    const float* rowp = in + ((size_t)(b0 + bl_st) * CINC + i_st) * ROWF;

    F4 sa, sb; float sc;
    auto issue_in = [&](int k) {
        const float* p = rowp + k * NX;
        sa = *(const F4*)p; sb = *(const F4*)(p + 4); sc = p[8];
    };
    issue_in(0);

    short* Ilb = Il + bl_st * (NX * LDK) + i_st;   // + x*LDK per x

    for (int k = 0; k < NK; ++k) {
        // ---- staged regs -> Il in x-order (compiler inserts counted vmcnt)
        Ilb[0 * LDK] = f2bf(sa.x);
        Ilb[1 * LDK] = f2bf(sa.y);
        Ilb[2 * LDK] = f2bf(sa.z);
        Ilb[3 * LDK] = f2bf(sa.w);
        Ilb[4 * LDK] = f2bf(sb.x);
        Ilb[5 * LDK] = f2bf(sb.y);
        Ilb[6 * LDK] = f2bf(sb.z);
        Ilb[7 * LDK] = f2bf(sb.w);
        Ilb[8 * LDK] = f2bf(sc);

        asm volatile("s_waitcnt lgkmcnt(0)" ::: "memory");
        __builtin_amdgcn_s_barrier();
        // (also orders prev tile's Ol copy-reads before this tile's scatter)

        // ---- W + bias loads FIRST (oldest in VMEM FIFO: the convert's wait
        // completes without draining the input prefetch issued after them)
        const float* wp = w + k * (COUTC * CINC) + (oc_base + lc) * CINC + quad * 8;
        float4 w0[4], w1[4];
        #pragma unroll
        for (int s = 0; s < 4; ++s) {
            w0[s] = *(const float4*)(wp + s * 32);
            w1[s] = *(const float4*)(wp + s * 32 + 4);
        }
        const float* bp = bias + k * COUTC + oc_base + quad * 4;
        float bsv[4];
        #pragma unroll
        for (int r = 0; r < 4; ++r) bsv[r] = bp[r];
        __builtin_amdgcn_sched_barrier(0);
        // ---- input prefetch for next k: in flight through MFMA+epilogue.
        // Reads address-adjacent slice of the same rows -> L1/L2 hit.
        if (k < NK - 1) issue_in(k + 1);
        __builtin_amdgcn_sched_barrier(0);

        // ---- convert W (vmcnt wait reaches only the W/bias loads)
        short8 afr[4];
        #pragma unroll
        for (int s = 0; s < 4; ++s) {
            short8 a;
            a[0] = f2bf(w0[s].x); a[1] = f2bf(w0[s].y);
            a[2] = f2bf(w0[s].z); a[3] = f2bf(w0[s].w);
            a[4] = f2bf(w1[s].x); a[5] = f2bf(w1[s].y);
            a[6] = f2bf(w1[s].z); a[7] = f2bf(w1[s].w);
            afr[s] = a;
        }

        // ---- MFMA: M=16 (wave's oc), K=128, N=36: 2 full col-tiles + quarter
        // tile (lanes lc>=4 broadcast-read col 32+(lc&3); outputs 36..47
        // discarded). acc[3] keeps the register peak under the 64 cap.
        floatx4 acc[3];
        #pragma unroll
        for (int n = 0; n < 3; ++n) acc[n] = (floatx4){0.f, 0.f, 0.f, 0.f};
        #pragma unroll
        for (int s = 0; s < 4; ++s) {
            const int kof = s * 32 + quad * 8;
            #pragma unroll
            for (int n = 0; n < 3; ++n) {
                const int col = (n < 2) ? (n * 16 + lc) : (32 + (lc & 3));
                short8 bfr = *(const short8*)&Il[col * LDK + kof];
                acc[n] = __builtin_amdgcn_mfma_f32_16x16x32_bf16(afr[s], bfr, acc[n], 0, 0, 0);
            }
        }

        // ---- scatter acc+bias -> Ol[bl][oc][x]
        // C/D: col(lane&15)=nx -> (bl=nx/9, x=nx%9); row(quad*4+r)=oc offset.
        #pragma unroll
        for (int n = 0; n < 2; ++n) {
            int nx = n * 16 + lc;
            int bl = nx / 9;
            int x = nx - bl * 9;
            float* op = Ol + (bl * COUTC + oc_base + quad * 4) * NX + x;
            #pragma unroll
            for (int r = 0; r < 4; ++r) op[r * NX] = acc[n][r] + bsv[r];
        }
        if (lc < 4) {                   // n=2 valid cols: nx=32..35 -> bl=3, x=5..8
            float* op = Ol + (3 * COUTC + oc_base + quad * 4) * NX + 5 + lc;
            #pragma unroll
            for (int r = 0; r < 4; ++r) op[r * NX] = acc[2][r] + bsv[r];
        }

        asm volatile("s_waitcnt lgkmcnt(0)" ::: "memory");
        __builtin_amdgcn_s_barrier();

        // ---- copy Ol -> out: 4608 floats = 1152 float4-chunks, dense per
        // instruction (lane stride 16B); stores stay in flight into next tile.
        float* dstk = out + (size_t)b0 * OUTB + k * OUTK;
        #pragma unroll
        for (int c = 0; c < 2; ++c) {
            int fo = (c * 512 + t) * 4;
            int bl = fo / 1152;
            int rem = fo - bl * 1152;
            floatx4 v = *(const floatx4*)(Ol + fo);
            *(floatx4*)(dstk + (size_t)bl * OUTB + rem) = v;
        }
        if (t < 128) {
            int fo = (1024 + t) * 4;          // floats 4096..4607 -> bl=3
            int rem = fo - 3 * 1152;
            floatx4 v = *(const floatx4*)(Ol + fo);
            *(floatx4*)(dstk + (size_t)3 * OUTB + rem) = v;
        }
        // next tile's Il writes are ordered behind this copy's Ol ds_reads by
        // the lgkm(0)+barrier at loop top.
    }
}

extern "C" void kernel_launch(void* const* d_in, const int* in_sizes, int n_in,
                              void* d_out, int out_size, void* d_ws, size_t ws_size,
                              hipStream_t stream) {
    const float* in  = (const float*)d_in[0];
    const float* w   = (const float*)d_in[1];
    const float* bs  = (const float*)d_in[2];
    float* out = (float*)d_out;
    dim3 grid(NB / BT);     // 1024 blocks = exactly one 4-blocks/CU round
    dim3 block(512);
    GatherVertical_40656160424516_kernel<<<grid, block, 0, stream>>>(in, w, bs, out);
}

// Round 8
// 374.161 us; speedup vs baseline: 1.2089x; 1.2089x over previous
//
#include <hip/hip_runtime.h>
#include <hip/hip_bf16.h>

// out[b,k,oc,x] = sum_i W[k,oc,i] * in[b,i,k,x] + bias[k,oc]
// B=4096, Cin=Cout=128, K(offsets)=9, X=9.
// Memory-bound. Traffic floor ~370 MB -> ~60us @6.2TB/s.
// R1: XCD swizzle + W direct.                      (158us)
// R2: deep-MLP staging -> null.                    (164us)
// R3: LDS-relayout coalesced stores -> -13%.       (143us)
// R4: all-k 512-thr blocks -> regression.          (249us)
// R5: 64-reg cap -> spill.                         (322us)
// R6: pipeline, LDS slot bug.                      (failed)
// R7: pipeline works: 2.97 TB/s, time==bytes/BW. KG=3 FETCH amp 1.6x. (151us)
// R8: KG=9/BT=4 at 64-reg cap -> spill again (live peak ~79: W staging
//     w0/w1=32 regs is the hog). WRITE 307/FETCH 507 MB.            (261us)
// R9: shrink the working set instead of capping the allocator:
//     pre-pass kernel converts W f32->bf16 row-major into d_ws (~5us);
//     main kernel loads A-fragments as 4 direct short8 (16 regs, no convert),
//     bias as one float4. Live peak ~55 -> fits 64 regs honestly at (512,8):
//     4 blk/CU, 100% nominal occupancy, KG=9 kills the FETCH amplification.
//     Pipeline (FIFO W-before-prefetch, lgkm-only barriers) unchanged.
//     Fallback (ws too small): R8 body at (512,4) - no spill, R7-class.

#define NB    4096
#define CINC  128
#define COUTC 128
#define NK    9
#define NX    9
#define BT    4                // b's per block
#define NCOL  (BT * NX)        // 36 cols
#define LDK   136              // padded i-stride (shorts)
#define ROWF  (NK * NX)        // 81 floats per (b,i) row
#define OUTK  (COUTC * NX)     // 1152 floats per (b,k)
#define OUTB  (NK * OUTK)
#define NWELT (NK * COUTC * CINC)   // 147456 W elements

typedef __attribute__((ext_vector_type(8))) short short8;
typedef __attribute__((ext_vector_type(4))) float floatx4;

struct F4 { float x, y, z, w; };   // 16B payload, 4B-aligned -> global_load_dwordx4

__device__ __forceinline__ short f2bf(float f) {
    union { float f; unsigned u; } v; v.f = f;
    unsigned r = v.u + 0x7fff + ((v.u >> 16) & 1);  // RNE; inputs finite normals
    return (short)(r >> 16);
}

// ---- pre-pass: W f32 -> bf16, row-major [k][oc][i] (main kernel's natural
// fragment layout: thread's short8 = 16B contiguous). 147456 elts, ~5us.
__global__ __launch_bounds__(256) void GatherVertical_40656160424516_wconv(
    const float* __restrict__ w, short* __restrict__ wbf)
{
    int idx = blockIdx.x * 256 + threadIdx.x;
    wbf[idx] = f2bf(w[idx]);
}

__global__ __launch_bounds__(512, 8) void GatherVertical_40656160424516_kernel(
    const float* __restrict__ in, const short* __restrict__ wbf,
    const float* __restrict__ bias, float* __restrict__ out)
{
    // Il: bf16 [col=bl*9+x : 36][i : LDK] =  9792 B  (MFMA operand tile)
    // Ol: f32  [bl : 4][oc : 128][x : 9]  = 18432 B  (epilogue relayout)
    // 28224 B -> 4 blocks/CU (wave-limited), 100% nominal occupancy.
    __shared__ __align__(16) char smem[NCOL * LDK * 2 + BT * OUTK * 4];
    short* Il = (short*)smem;
    float* Ol = (float*)(smem + NCOL * LDK * 2);

    const int t = threadIdx.x;
    const int b0 = blockIdx.x * BT;   // blocks fully private: no swizzle needed

    const int lane = t & 63;
    const int wv = t >> 6;            // 0..7: wave's 16 oc rows
    const int lc = lane & 15;
    const int quad = lane >> 4;
    const int oc_base = wv * 16;

    // ---- staging: thread t owns row (bl = t>>7, i = t&127). Per k-tile:
    // 2x dwordx4 + 1 dword (36B slice), 9 ds_write_b16 at base + imm offsets
    // (lanes = consecutive i -> 2-way bank alias = free).
    const int i_st = t & 127;
    const int bl_st = t >> 7;
    const float* rowp = in + ((size_t)(b0 + bl_st) * CINC + i_st) * ROWF;

    F4 sa, sb; float sc;
    auto issue_in = [&](int k) {
        const float* p = rowp + k * NX;
        sa = *(const F4*)p; sb = *(const F4*)(p + 4); sc = p[8];
    };
    issue_in(0);

    short* Ilb = Il + bl_st * (NX * LDK) + i_st;   // + x*LDK per x

    for (int k = 0; k < NK; ++k) {
        // ---- staged regs -> Il in x-order (compiler inserts counted vmcnt)
        Ilb[0 * LDK] = f2bf(sa.x);
        Ilb[1 * LDK] = f2bf(sa.y);
        Ilb[2 * LDK] = f2bf(sa.z);
        Ilb[3 * LDK] = f2bf(sa.w);
        Ilb[4 * LDK] = f2bf(sb.x);
        Ilb[5 * LDK] = f2bf(sb.y);
        Ilb[6 * LDK] = f2bf(sb.z);
        Ilb[7 * LDK] = f2bf(sb.w);
        Ilb[8 * LDK] = f2bf(sc);

        asm volatile("s_waitcnt lgkmcnt(0)" ::: "memory");
        __builtin_amdgcn_s_barrier();
        // (also orders prev tile's Ol copy-reads before this tile's scatter)

        // ---- A-fragments + bias: direct bf16/f32, issued FIRST (oldest in
        // VMEM FIFO: their waits complete leaving the input prefetch in flight)
        const short* wpk = wbf + k * (COUTC * CINC) + (oc_base + lc) * CINC + quad * 8;
        short8 afr[4];
        #pragma unroll
        for (int s = 0; s < 4; ++s) afr[s] = *(const short8*)(wpk + s * 32);
        float4 bv = *(const float4*)(bias + k * COUTC + oc_base + quad * 4);
        __builtin_amdgcn_sched_barrier(0);
        // ---- input prefetch for next k: address-adjacent 36B slice of the
        // same rows (L1/L2-hit); in flight through MFMA+epilogue.
        if (k < NK - 1) issue_in(k + 1);
        __builtin_amdgcn_sched_barrier(0);

        float bsv[4] = {bv.x, bv.y, bv.z, bv.w};

        // ---- MFMA: M=16 (wave's oc), K=128, N=36: 2 full col-tiles + quarter
        // tile (lanes lc>=4 broadcast-read col 32+(lc&3); outputs discarded).
        floatx4 acc[3];
        #pragma unroll
        for (int n = 0; n < 3; ++n) acc[n] = (floatx4){0.f, 0.f, 0.f, 0.f};
        #pragma unroll
        for (int s = 0; s < 4; ++s) {
            const int kof = s * 32 + quad * 8;
            #pragma unroll
            for (int n = 0; n < 3; ++n) {
                const int col = (n < 2) ? (n * 16 + lc) : (32 + (lc & 3));
                short8 bfr = *(const short8*)&Il[col * LDK + kof];
                acc[n] = __builtin_amdgcn_mfma_f32_16x16x32_bf16(afr[s], bfr, acc[n], 0, 0, 0);
            }
        }

        // ---- scatter acc+bias -> Ol[bl][oc][x]
        // C/D: col(lane&15)=nx -> (bl=nx/9, x=nx%9); row(quad*4+r)=oc offset.
        #pragma unroll
        for (int n = 0; n < 2; ++n) {
            int nx = n * 16 + lc;
            int bl = nx / 9;
            int x = nx - bl * 9;
            float* op = Ol + (bl * COUTC + oc_base + quad * 4) * NX + x;
            #pragma unroll
            for (int r = 0; r < 4; ++r) op[r * NX] = acc[n][r] + bsv[r];
        }
        if (lc < 4) {                   // n=2 valid cols: nx=32..35 -> bl=3, x=5..8
            float* op = Ol + (3 * COUTC + oc_base + quad * 4) * NX + 5 + lc;
            #pragma unroll
            for (int r = 0; r < 4; ++r) op[r * NX] = acc[2][r] + bsv[r];
        }

        asm volatile("s_waitcnt lgkmcnt(0)" ::: "memory");
        __builtin_amdgcn_s_barrier();

        // ---- copy Ol -> out: 4608 floats = 1152 float4-chunks; stores stay
        // in flight into the next tile.
        float* dstk = out + (size_t)b0 * OUTB + k * OUTK;
        #pragma unroll
        for (int c = 0; c < 2; ++c) {
            int fo = (c * 512 + t) * 4;
            int bl = fo / 1152;
            int rem = fo - bl * 1152;
            floatx4 v = *(const floatx4*)(Ol + fo);
            *(floatx4*)(dstk + (size_t)bl * OUTB + rem) = v;
        }
        if (t < 128) {
            int fo = (1024 + t) * 4;          // floats 4096..4607 -> bl=3
            int rem = fo - 3 * 1152;
            floatx4 v = *(const floatx4*)(Ol + fo);
            *(floatx4*)(dstk + (size_t)3 * OUTB + rem) = v;
        }
        // next tile's Il writes are ordered behind this copy's Ol ds_reads by
        // the lgkm(0)+barrier at loop top.
    }
}

// ---- fallback (workspace too small): R8 body, f32 W staging, (512,4) budget
// -> no spill (R7-measured 60-80 regs fits 128), ~2 blk/CU.
__global__ __launch_bounds__(512, 4) void GatherVertical_40656160424516_fb(
    const float* __restrict__ in, const float* __restrict__ w,
    const float* __restrict__ bias, float* __restrict__ out)
{
    __shared__ __align__(16) char smem[NCOL * LDK * 2 + BT * OUTK * 4];
    short* Il = (short*)smem;
    float* Ol = (float*)(smem + NCOL * LDK * 2);

    const int t = threadIdx.x;
    const int b0 = blockIdx.x * BT;
    const int lane = t & 63;
    const int wv = t >> 6;
    const int lc = lane & 15;
    const int quad = lane >> 4;
    const int oc_base = wv * 16;

    const int i_st = t & 127;
    const int bl_st = t >> 7;
    const float* rowp = in + ((size_t)(b0 + bl_st) * CINC + i_st) * ROWF;

    F4 sa, sb; float sc;
    auto issue_in = [&](int k) {
        const float* p = rowp + k * NX;
        sa = *(const F4*)p; sb = *(const F4*)(p + 4); sc = p[8];
    };
    issue_in(0);
    short* Ilb = Il + bl_st * (NX * LDK) + i_st;

    for (int k = 0; k < NK; ++k) {
        Ilb[0 * LDK] = f2bf(sa.x); Ilb[1 * LDK] = f2bf(sa.y);
        Ilb[2 * LDK] = f2bf(sa.z); Ilb[3 * LDK] = f2bf(sa.w);
        Ilb[4 * LDK] = f2bf(sb.x); Ilb[5 * LDK] = f2bf(sb.y);
        Ilb[6 * LDK] = f2bf(sb.z); Ilb[7 * LDK] = f2bf(sb.w);
        Ilb[8 * LDK] = f2bf(sc);

        asm volatile("s_waitcnt lgkmcnt(0)" ::: "memory");
        __builtin_amdgcn_s_barrier();

        const float* wp = w + k * (COUTC * CINC) + (oc_base + lc) * CINC + quad * 8;
        float4 w0[4], w1[4];
        #pragma unroll
        for (int s = 0; s < 4; ++s) {
            w0[s] = *(const float4*)(wp + s * 32);
            w1[s] = *(const float4*)(wp + s * 32 + 4);
        }
        float4 bv = *(const float4*)(bias + k * COUTC + oc_base + quad * 4);
        __builtin_amdgcn_sched_barrier(0);
        if (k < NK - 1) issue_in(k + 1);
        __builtin_amdgcn_sched_barrier(0);

        short8 afr[4];
        #pragma unroll
        for (int s = 0; s < 4; ++s) {
            short8 a;
            a[0] = f2bf(w0[s].x); a[1] = f2bf(w0[s].y);
            a[2] = f2bf(w0[s].z); a[3] = f2bf(w0[s].w);
            a[4] = f2bf(w1[s].x); a[5] = f2bf(w1[s].y);
            a[6] = f2bf(w1[s].z); a[7] = f2bf(w1[s].w);
            afr[s] = a;
        }
        float bsv[4] = {bv.x, bv.y, bv.z, bv.w};

        floatx4 acc[3];
        #pragma unroll
        for (int n = 0; n < 3; ++n) acc[n] = (floatx4){0.f, 0.f, 0.f, 0.f};
        #pragma unroll
        for (int s = 0; s < 4; ++s) {
            const int kof = s * 32 + quad * 8;
            #pragma unroll
            for (int n = 0; n < 3; ++n) {
                const int col = (n < 2) ? (n * 16 + lc) : (32 + (lc & 3));
                short8 bfr = *(const short8*)&Il[col * LDK + kof];
                acc[n] = __builtin_amdgcn_mfma_f32_16x16x32_bf16(afr[s], bfr, acc[n], 0, 0, 0);
            }
        }

        #pragma unroll
        for (int n = 0; n < 2; ++n) {
            int nx = n * 16 + lc;
            int bl = nx / 9;
            int x = nx - bl * 9;
            float* op = Ol + (bl * COUTC + oc_base + quad * 4) * NX + x;
            #pragma unroll
            for (int r = 0; r < 4; ++r) op[r * NX] = acc[n][r] + bsv[r];
        }
        if (lc < 4) {
            float* op = Ol + (3 * COUTC + oc_base + quad * 4) * NX + 5 + lc;
            #pragma unroll
            for (int r = 0; r < 4; ++r) op[r * NX] = acc[2][r] + bsv[r];
        }

        asm volatile("s_waitcnt lgkmcnt(0)" ::: "memory");
        __builtin_amdgcn_s_barrier();

        float* dstk = out + (size_t)b0 * OUTB + k * OUTK;
        #pragma unroll
        for (int c = 0; c < 2; ++c) {
            int fo = (c * 512 + t) * 4;
            int bl = fo / 1152;
            int rem = fo - bl * 1152;
            floatx4 v = *(const floatx4*)(Ol + fo);
            *(floatx4*)(dstk + (size_t)bl * OUTB + rem) = v;
        }
        if (t < 128) {
            int fo = (1024 + t) * 4;
            int rem = fo - 3 * 1152;
            floatx4 v = *(const floatx4*)(Ol + fo);
            *(floatx4*)(dstk + (size_t)3 * OUTB + rem) = v;
        }
    }
}

extern "C" void kernel_launch(void* const* d_in, const int* in_sizes, int n_in,
                              void* d_out, int out_size, void* d_ws, size_t ws_size,
                              hipStream_t stream) {
    const float* in  = (const float*)d_in[0];
    const float* w   = (const float*)d_in[1];
    const float* bs  = (const float*)d_in[2];
    float* out = (float*)d_out;
    const size_t WBF_BYTES = (size_t)NWELT * sizeof(short);   // 294912 B
    if (d_ws != nullptr && ws_size >= WBF_BYTES) {
        short* wbf = (short*)d_ws;
        GatherVertical_40656160424516_wconv<<<NWELT / 256, 256, 0, stream>>>(w, wbf);
        GatherVertical_40656160424516_kernel<<<NB / BT, 512, 0, stream>>>(in, wbf, bs, out);
    } else {
        GatherVertical_40656160424516_fb<<<NB / BT, 512, 0, stream>>>(in, w, bs, out);
    }
}

// Round 9
// 351.296 us; speedup vs baseline: 1.2876x; 1.0651x over previous
//
#include <hip/hip_runtime.h>
#include <hip/hip_bf16.h>

// out[b,k,oc,x] = sum_i W[k,oc,i] * in[b,i,k,x] + bias[k,oc]
// B=4096, Cin=Cout=128, K(offsets)=9, X=9.
// Memory-bound. Traffic floor ~345 MB -> ~57us @6TB/s.
// R1: XCD swizzle + W direct.                         (158us)
// R2: deep-MLP staging -> null.                       (164us)
// R3: LDS-relayout coalesced stores -> -13%.          (143us)
// R4: all-k staging: FETCH hit the 158MB floor, but f32-W staging spilled
//     (WRITE 282MB) -> slow. Read structure was RIGHT, regs were wrong. (249us)
// R5: 64-reg cap -> spill.                            (322us)
// R6: pipeline, LDS slot bug.                         (failed)
// R7: pipeline works: 2.97 TB/s, time==bytes/BW. KG=3 FETCH amp 1.6x. (151us)
// R8: KG=9/BT=4, 64-reg cap -> spill again.           (261us)
// R9: wbf pre-pass killed the spill, but KG=9 via-cache k-reuse FAILED:
//     slices 19us apart, L2 churns 5MB/step -> FETCH 308MB.         (175us)
// R10: combine the three proven pieces: R4's stage-all-9-k-once-in-LDS
//     (read floor: every input line fetched exactly once, zero cross-k cache
//     dependence) + R9's bf16-W pre-pass (A-frags = 4 direct short8, no
//     32-reg f32 staging) + R3 relayout epilogue (write floor). No tight reg
//     cap: (512,6) ~85 regs for ~55 live; LDS 53.3KB caps at 3 blk/CU anyway.

#define NB    4096
#define CINC  128
#define COUTC 128
#define NK    9
#define NX    9
#define BT    2
#define ROWF  (NK * NX)            // 81 floats per (b,i) row
#define LDK   136                  // padded i-stride (shorts), 16B-aligned rows
#define KSTR  (18 * LDK)           // 2448 shorts: k-stride in Il
#define OUTK  (COUTC * NX)         // 1152 floats per (b,k)
#define OUTB  (NK * OUTK)
#define NWELT (NK * COUTC * CINC)  // 147456 W elements

typedef __attribute__((ext_vector_type(8))) short short8;
typedef __attribute__((ext_vector_type(4))) float floatx4;

struct F4 { float x, y, z, w; };   // 16B payload, 4B-aligned -> global_load_dwordx4

__device__ __forceinline__ short f2bf(float f) {
    union { float f; unsigned u; } v; v.f = f;
    unsigned r = v.u + 0x7fff + ((v.u >> 16) & 1);  // RNE; inputs finite normals
    return (short)(r >> 16);
}

// LDS offset (shorts, relative to Il + bb*9*LDK + i) for flat kx = k*9+x
__device__ __forceinline__ constexpr int koff(int kx) {
    return (kx / 9) * KSTR + (kx % 9) * LDK;
}

// Load 20 floats (5x dwordx4), transpose-write bf16 at compile-time offsets.
// KX0 = flat (k*9+x) index of p[0]. (R4-verified.)
template<int KX0>
__device__ __forceinline__ void stage20(short* lb, const float* p) {
    F4 v[5];
    #pragma unroll
    for (int c = 0; c < 5; ++c) v[c] = *(const F4*)(p + 4 * c);
    #pragma unroll
    for (int c = 0; c < 5; ++c) {
        lb[koff(KX0 + 4 * c + 0)] = f2bf(v[c].x);
        lb[koff(KX0 + 4 * c + 1)] = f2bf(v[c].y);
        lb[koff(KX0 + 4 * c + 2)] = f2bf(v[c].z);
        lb[koff(KX0 + 4 * c + 3)] = f2bf(v[c].w);
    }
}

// ---- pre-pass: W f32 -> bf16 row-major [k][oc][i]. 147456 elts, ~5us.
__global__ __launch_bounds__(256) void GatherVertical_40656160424516_wconv(
    const float* __restrict__ w, short* __restrict__ wbf)
{
    int idx = blockIdx.x * 256 + threadIdx.x;
    wbf[idx] = f2bf(w[idx]);
}

__global__ __launch_bounds__(512, 6) void GatherVertical_40656160424516_kernel(
    const float* __restrict__ in, const short* __restrict__ wbf,
    const float* __restrict__ bias, float* __restrict__ out)
{
    // Il: bf16 [k=9][col=bb*9+x : 18][i : LDK] = 44064 B (all-k input tile)
    // Ol: f32  [bb=2][oc=128][x=9]             =  9216 B (epilogue relayout)
    // 53280 B -> 3 blocks/CU (24 waves, LDS-limited).
    __shared__ __align__(16) char smem[9 * KSTR * 2 + BT * OUTK * 4];
    short* Il = (short*)smem;
    float* Ol = (float*)(smem + 9 * KSTR * 2);

    const int t = threadIdx.x;
    const int b0 = blockIdx.x * BT;   // blocks fully input-private: no swizzle

    const int lane = t & 63;
    const int wv = t >> 6;
    const int lc = lane & 15;
    const int quad = lane >> 4;
    const int oc_base = wv * 16;      // wave's 16 oc rows

    // ---- stage ALL 9 k's once: thread owns half of row (b=bb, i):
    // floats [40h, 40h+40+h). h, bb wave-uniform -> immediate LDS offsets.
    // Whole block reads one contiguous 83KB span; each line fetched once.
    {
        const int r = t & 255;
        const int h = t >> 8;
        const int bb = r >> 7;
        const int i = r & 127;
        const float* rowp = in + ((size_t)(b0 + bb) * CINC + i) * ROWF + 40 * h;
        short* lb = Il + bb * (NX * LDK) + i;
        if (h == 0) {
            stage20<0>(lb, rowp);
            stage20<20>(lb, rowp + 20);
        } else {
            stage20<40>(lb, rowp);
            stage20<60>(lb, rowp + 20);
            lb[koff(80)] = f2bf(rowp[40]);          // 81st element
        }
    }

    asm volatile("s_waitcnt lgkmcnt(0)" ::: "memory");
    __builtin_amdgcn_s_barrier();

    for (int k = 0; k < NK; ++k) {
        // ---- A-fragments + bias: direct bf16/f32 from L2-resident wbf.
        const short* wpk = wbf + k * (COUTC * CINC) + (oc_base + lc) * CINC + quad * 8;
        short8 afr[4];
        #pragma unroll
        for (int s = 0; s < 4; ++s) afr[s] = *(const short8*)(wpk + s * 32);
        float4 bv = *(const float4*)(bias + k * COUTC + oc_base + quad * 4);
        float bsv[4] = {bv.x, bv.y, bv.z, bv.w};

        // ---- MFMA: M=16 (wave's oc), K=128, N=18 as 2 col-tiles.
        // B-frag: lane holds B[kk=quad*8+e+32s][col] from Il[k][col][i].
        // Tile1 cols 18..31 read garbage (stays inside smem; outputs never
        // stored). Reads of Il are hazard-free all kernel (written once).
        floatx4 acc0 = {0.f, 0.f, 0.f, 0.f};
        floatx4 acc1 = {0.f, 0.f, 0.f, 0.f};
        const short* bp = Il + k * KSTR + lc * LDK + quad * 8;
        #pragma unroll
        for (int s = 0; s < 4; ++s) {
            short8 bf0 = *(const short8*)(bp + s * 32);
            short8 bf1 = *(const short8*)(bp + 16 * LDK + s * 32);
            acc0 = __builtin_amdgcn_mfma_f32_16x16x32_bf16(afr[s], bf0, acc0, 0, 0, 0);
            acc1 = __builtin_amdgcn_mfma_f32_16x16x32_bf16(afr[s], bf1, acc1, 0, 0, 0);
        }

        asm volatile("s_waitcnt lgkmcnt(0)" ::: "memory");
        __builtin_amdgcn_s_barrier();
        // barrier A: previous iteration's copy ds_reads (own: by lgkm(0);
        // others: by barrier) complete before scatter overwrites Ol.

        // ---- scatter acc+bias -> Ol[bb][oc][x]
        // C/D: col(lane&15)=nx; tile0: nx=lc -> (bb=lc>=9, x=lc-9bb);
        // tile1 valid cols 16,17 -> bb=1, x=7,8. row(quad*4+rr)=oc offset.
        {
            int bcp = lc >= 9;
            int x = lc - bcp * 9;
            float* op = Ol + (bcp * COUTC + oc_base + quad * 4) * NX + x;
            #pragma unroll
            for (int rr = 0; rr < 4; ++rr) op[rr * NX] = acc0[rr] + bsv[rr];
            if (lc < 2) {
                float* op1 = Ol + (COUTC + oc_base + quad * 4) * NX + 7 + lc;
                #pragma unroll
                for (int rr = 0; rr < 4; ++rr) op1[rr * NX] = acc1[rr] + bsv[rr];
            }
        }

        asm volatile("s_waitcnt lgkmcnt(0)" ::: "memory");
        __builtin_amdgcn_s_barrier();
        // barrier B: scatter visible to all before copy reads.

        // ---- copy Ol -> out: two contiguous 4608B line-aligned runs per k;
        // 576 float4-chunks over 512 threads. Stores stream into next k
        // (no vmcnt drain anywhere in the loop).
        {
            float* dstb = out + (size_t)b0 * OUTB + k * OUTK;
            int bcp = t >= 288;
            int off = (t - bcp * 288) * 4;
            floatx4 v = *(const floatx4*)(Ol + bcp * OUTK + off);
            *(floatx4*)(dstb + (size_t)bcp * OUTB + off) = v;
            if (t < 64) {
                int off2 = (224 + t) * 4;
                floatx4 v2 = *(const floatx4*)(Ol + OUTK + off2);
                *(floatx4*)(dstb + (size_t)OUTB + off2) = v2;
            }
        }
    }
}

// ---- fallback (workspace too small): R9's fb, proven pass, R7-class.
__global__ __launch_bounds__(512, 4) void GatherVertical_40656160424516_fb(
    const float* __restrict__ in, const float* __restrict__ w,
    const float* __restrict__ bias, float* __restrict__ out)
{
    __shared__ __align__(16) char smem2[36 * LDK * 2 + 4 * OUTK * 4];
    short* Il = (short*)smem2;
    float* Ol = (float*)(smem2 + 36 * LDK * 2);

    const int t = threadIdx.x;
    const int b0 = blockIdx.x * 4;
    const int lane = t & 63;
    const int wv = t >> 6;
    const int lc = lane & 15;
    const int quad = lane >> 4;
    const int oc_base = wv * 16;

    const int i_st = t & 127;
    const int bl_st = t >> 7;
    const float* rowp = in + ((size_t)(b0 + bl_st) * CINC + i_st) * ROWF;

    F4 sa, sb; float sc;
    auto issue_in = [&](int k) {
        const float* p = rowp + k * NX;
        sa = *(const F4*)p; sb = *(const F4*)(p + 4); sc = p[8];
    };
    issue_in(0);
    short* Ilb = Il + bl_st * (NX * LDK) + i_st;

    for (int k = 0; k < NK; ++k) {
        Ilb[0 * LDK] = f2bf(sa.x); Ilb[1 * LDK] = f2bf(sa.y);
        Ilb[2 * LDK] = f2bf(sa.z); Ilb[3 * LDK] = f2bf(sa.w);
        Ilb[4 * LDK] = f2bf(sb.x); Ilb[5 * LDK] = f2bf(sb.y);
        Ilb[6 * LDK] = f2bf(sb.z); Ilb[7 * LDK] = f2bf(sb.w);
        Ilb[8 * LDK] = f2bf(sc);

        asm volatile("s_waitcnt lgkmcnt(0)" ::: "memory");
        __builtin_amdgcn_s_barrier();

        const float* wp = w + k * (COUTC * CINC) + (oc_base + lc) * CINC + quad * 8;
        float4 w0[4], w1[4];
        #pragma unroll
        for (int s = 0; s < 4; ++s) {
            w0[s] = *(const float4*)(wp + s * 32);
            w1[s] = *(const float4*)(wp + s * 32 + 4);
        }
        float4 bv = *(const float4*)(bias + k * COUTC + oc_base + quad * 4);
        __builtin_amdgcn_sched_barrier(0);
        if (k < NK - 1) issue_in(k + 1);
        __builtin_amdgcn_sched_barrier(0);

        short8 afr[4];
        #pragma unroll
        for (int s = 0; s < 4; ++s) {
            short8 a;
            a[0] = f2bf(w0[s].x); a[1] = f2bf(w0[s].y);
            a[2] = f2bf(w0[s].z); a[3] = f2bf(w0[s].w);
            a[4] = f2bf(w1[s].x); a[5] = f2bf(w1[s].y);
            a[6] = f2bf(w1[s].z); a[7] = f2bf(w1[s].w);
            afr[s] = a;
        }
        float bsv[4] = {bv.x, bv.y, bv.z, bv.w};

        floatx4 acc[3];
        #pragma unroll
        for (int n = 0; n < 3; ++n) acc[n] = (floatx4){0.f, 0.f, 0.f, 0.f};
        #pragma unroll
        for (int s = 0; s < 4; ++s) {
            const int kof = s * 32 + quad * 8;
            #pragma unroll
            for (int n = 0; n < 3; ++n) {
                const int col = (n < 2) ? (n * 16 + lc) : (32 + (lc & 3));
                short8 bfr = *(const short8*)&Il[col * LDK + kof];
                acc[n] = __builtin_amdgcn_mfma_f32_16x16x32_bf16(afr[s], bfr, acc[n], 0, 0, 0);
            }
        }

        #pragma unroll
        for (int n = 0; n < 2; ++n) {
            int nx = n * 16 + lc;
            int bl = nx / 9;
            int x = nx - bl * 9;
            float* op = Ol + (bl * COUTC + oc_base + quad * 4) * NX + x;
            #pragma unroll
            for (int r = 0; r < 4; ++r) op[r * NX] = acc[n][r] + bsv[r];
        }
        if (lc < 4) {
            float* op = Ol + (3 * COUTC + oc_base + quad * 4) * NX + 5 + lc;
            #pragma unroll
            for (int r = 0; r < 4; ++r) op[r * NX] = acc[2][r] + bsv[r];
        }

        asm volatile("s_waitcnt lgkmcnt(0)" ::: "memory");
        __builtin_amdgcn_s_barrier();

        float* dstk = out + (size_t)b0 * OUTB + k * OUTK;
        #pragma unroll
        for (int c = 0; c < 2; ++c) {
            int fo = (c * 512 + t) * 4;
            int bl = fo / 1152;
            int rem = fo - bl * 1152;
            floatx4 v = *(const floatx4*)(Ol + fo);
            *(floatx4*)(dstk + (size_t)bl * OUTB + rem) = v;
        }
        if (t < 128) {
            int fo = (1024 + t) * 4;
            int rem = fo - 3 * 1152;
            floatx4 v = *(const floatx4*)(Ol + fo);
            *(floatx4*)(dstk + (size_t)3 * OUTB + rem) = v;
        }
    }
}

extern "C" void kernel_launch(void* const* d_in, const int* in_sizes, int n_in,
                              void* d_out, int out_size, void* d_ws, size_t ws_size,
                              hipStream_t stream) {
    const float* in  = (const float*)d_in[0];
    const float* w   = (const float*)d_in[1];
    const float* bs  = (const float*)d_in[2];
    float* out = (float*)d_out;
    const size_t WBF_BYTES = (size_t)NWELT * sizeof(short);   // 294912 B
    if (d_ws != nullptr && ws_size >= WBF_BYTES) {
        short* wbf = (short*)d_ws;
        GatherVertical_40656160424516_wconv<<<NWELT / 256, 256, 0, stream>>>(w, wbf);
        GatherVertical_40656160424516_kernel<<<NB / BT, 512, 0, stream>>>(in, wbf, bs, out);
    } else {
        GatherVertical_40656160424516_fb<<<NB / 4, 512, 0, stream>>>(in, w, bs, out);
    }
}